// Round 9
// baseline (352.761 us; speedup 1.0000x reference)
//
#include <hip/hip_runtime.h>

#define C_ 512
#define L_ 784
#define K_ 64
#define EPS_ 1e-12f

typedef _Float16 half_t;
typedef _Float16 half4 __attribute__((ext_vector_type(4)));
typedef float float4v __attribute__((ext_vector_type(4)));

// ---------------------------------------------------------------------------
// kF v7 (resubmit; r8 was a GPU-acquisition infra failure, kernel never ran):
// v6's proven 2-barrier skeleton, restructured for 2 BLOCKS/CU
// (r7 post-mortem: 256 blocks = 1/CU meant every barrier drained the whole
// CU with nothing co-resident to fill the stall).
//   - grid (8, 64) = 512 blocks, l-chunk 96 (112 for bx=7): 6-7 subtiles
//   - xs staged in fp16: LDS 84 -> 51.5 KB (2 blocks/CU fits 103 KB < 160),
//     and readers consume half4 directly (32 v_cvt/wave/subtile deleted)
//   - __launch_bounds__(1024, 8): 8 waves/EU min => VGPR capped at 64
//     (compiler already picks 64; live set ~50 after cvt removal)
// Per 16-l subtile s (two barriers):
//   0. g0,g1 = dwordx4 loads for subtile s+1 (transient; sched_barrier pin)
//   1. bn[i] = ds_read half4 from xs[s&1]; logits: T = mfma(bn,I) transpose,
//      lc[i&3] += mfma(T_h, wf[i])
//   2. sl[l][k][cs] partials; barrier A
//   3. softmax: wave=l-row, lane=k, shfl_xor trees; ah[k][l]; asum
//   4. cvt g0,g1 -> half4, ds_write -> xs[(s+1)&1]  (epoch A..B; read after B)
//   5. barrier B; agg: agc[i] += mfma(A=ah, B=bn[i])  (bn still in regs)
// MFMA maps verified end-to-end r3/r4/r6/r7 (passed, absmax 1.2e-4):
//   A: m=lane&15, kk=q*4+j; B: n=lane&15, kk=q*4+j; D: row=q*4+r, col=lane&15.
// ---------------------------------------------------------------------------
__global__ __launch_bounds__(1024, 8) void kF(const float* __restrict__ x,
                                              const float* __restrict__ w,
                                              float* __restrict__ aggP,
                                              float* __restrict__ asumP) {
    __shared__ half_t xs[2][32 * 256];   // 32 KB: [buf][tile = cs*8+i][slot*4] fp16
    __shared__ float  sl[16 * 64 * 4];   // 16 KB: [l][k][cs] partials / asum buf
    __shared__ half_t ah[64 * 20];       // 2.5 KB: a fp16 [k][16 l + pad]

    const int t    = threadIdx.x;
    const int n    = blockIdx.y;
    const int bx   = blockIdx.x;
    const int l0   = bx * 96;
    const int NT   = (bx == 7) ? 7 : 6;   // 7*96 + 112 = 784
    const int wv   = t >> 6;
    const int lane = t & 63;
    const int m16  = lane & 15;
    const int q    = lane >> 4;
    const int kt   = wv & 3;   // k-tile (16 k)
    const int cs   = wv >> 2;  // c-segment (128 c = 8 tiles of 16)

    const float* xn = x + (size_t)n * (C_ * L_);

    // staging assignment: wave wv owns tiles T0 = 2wv, T0+1 (tile T: cs=T>>3, i=T&7)
    const int T0 = 2 * wv;
    const float* src0 = xn + (size_t)((T0 >> 3) * 128 + (T0 & 7) * 16 + m16) * L_ + l0 + 4 * q;
    const float* src1 = xn + (size_t)(((T0 + 1) >> 3) * 128 + ((T0 + 1) & 7) * 16 + m16) * L_ + l0 + 4 * q;

    // stage subtile 0
    {
        float4v g0 = *(const float4v*)src0;
        float4v g1 = *(const float4v*)src1;
        *(half4*)&xs[0][T0 * 256 + lane * 4] =
            half4{(half_t)g0[0], (half_t)g0[1], (half_t)g0[2], (half_t)g0[3]};
        *(half4*)&xs[0][(T0 + 1) * 256 + lane * 4] =
            half4{(half_t)g1[0], (half_t)g1[1], (half_t)g1[2], (half_t)g1[3]};
    }

    // w fragments (B-style): lane m16 -> k row, elems j -> c = cs*128+i*16+4q+j
    half4 wf[8];
#pragma unroll
    for (int i = 0; i < 8; ++i) {
        float4v f = *(const float4v*)(w + (size_t)(kt * 16 + m16) * C_ +
                                      cs * 128 + i * 16 + 4 * q);
        wf[i] = half4{(half_t)f[0], (half_t)f[1], (half_t)f[2], (half_t)f[3]};
    }
    // identity B-fragment: I[kk=4q+j][n=m16]
    half4 ifr;
#pragma unroll
    for (int j = 0; j < 4; ++j) ifr[j] = (half_t)((4 * q + j == m16) ? 1.0f : 0.0f);

    const float4v z4 = {0.f, 0.f, 0.f, 0.f};
    float4v agc[8];
#pragma unroll
    for (int i = 0; i < 8; ++i) agc[i] = z4;
    float asum_reg = 0.f;

    __syncthreads();

    for (int s = 0; s < NT; ++s) {
        // 0. transient prefetch of subtile s+1 (2 dwordx4/wave; LDS-written at 4)
        float4v g0, g1;
        const bool pf = (s + 1 < NT);
        if (pf) {
            g0 = *(const float4v*)(src0 + 16 * (s + 1));
            g1 = *(const float4v*)(src1 + 16 * (s + 1));
        }
        __builtin_amdgcn_sched_barrier(0);   // pin load issue at loop top
        // 1. fragments for subtile s straight from LDS (half4, no cvt) + logits
        const half_t* xb = &xs[s & 1][(cs * 8) * 256];
        half4 bn[8];
        float4v lc[4] = {z4, z4, z4, z4};
#pragma unroll
        for (int i = 0; i < 8; ++i) {
            bn[i] = *(const half4*)&xb[i * 256 + lane * 4];
            float4v xt = __builtin_amdgcn_mfma_f32_16x16x16f16(bn[i], ifr, z4, 0, 0, 0);
            half4 a4 = {(half_t)xt[0], (half_t)xt[1], (half_t)xt[2], (half_t)xt[3]};
            lc[i & 3] = __builtin_amdgcn_mfma_f32_16x16x16f16(a4, wf[i], lc[i & 3], 0, 0, 0);
        }
        float4v lac = (lc[0] + lc[1]) + (lc[2] + lc[3]);
        // 2. D[l][k]: row 4q+r = l_local, col m16 = k_local
#pragma unroll
        for (int r = 0; r < 4; ++r)
            sl[((4 * q + r) * 64 + kt * 16 + m16) * 4 + cs] = lac[r];
        __syncthreads();   // barrier A
        // 3. softmax: wave wv = l-row, lane = k
        {
            float4v p4 = *(const float4v*)&sl[(wv * 64 + lane) * 4];
            float lg = p4[0] + p4[1] + p4[2] + p4[3];
            float mx = lg;
#pragma unroll
            for (int off = 32; off; off >>= 1) mx = fmaxf(mx, __shfl_xor(mx, off, 64));
            float e = __expf(lg - mx);
            float sm = e;
#pragma unroll
            for (int off = 32; off; off >>= 1) sm += __shfl_xor(sm, off, 64);
            float a = e / sm;
            asum_reg += a;
            ah[lane * 20 + wv] = (half_t)a;
        }
        // 4. cvt + write staged subtile s+1 into the other xs buffer (read after B)
        if (pf) {
            *(half4*)&xs[(s + 1) & 1][T0 * 256 + lane * 4] =
                half4{(half_t)g0[0], (half_t)g0[1], (half_t)g0[2], (half_t)g0[3]};
            *(half4*)&xs[(s + 1) & 1][(T0 + 1) * 256 + lane * 4] =
                half4{(half_t)g1[0], (half_t)g1[1], (half_t)g1[2], (half_t)g1[3]};
        }
        __syncthreads();   // barrier B
        // 5. agg: D[k][c] += a[k][l] * x[c][l], K=16; bn straight from regs
        half4 aA = *(const half4*)&ah[(kt * 16 + m16) * 20 + 4 * q];
#pragma unroll
        for (int i = 0; i < 8; ++i)
            agc[i] = __builtin_amdgcn_mfma_f32_16x16x16f16(aA, bn[i], agc[i], 0, 0, 0);
    }

    // ---- epilogue: asum reduce (sl reused) + direct coalesced agg stores ----
    sl[wv * 64 + lane] = asum_reg;
    __syncthreads();
    if (t < 64) {
        float s_ = 0.f;
#pragma unroll
        for (int j = 0; j < 16; ++j) s_ += sl[j * 64 + t];
        asumP[((size_t)n * 8 + bx) * 64 + t] = s_;
    }
    float* ap = aggP + (((size_t)n * 8 + bx) * 64) * (size_t)C_;
#pragma unroll
    for (int i = 0; i < 8; ++i)
#pragma unroll
        for (int r = 0; r < 4; ++r)
            ap[(size_t)(kt * 16 + 4 * q + r) * C_ + (cs * 8 + i) * 16 + m16] = agc[i][r];
}

// ---------------------------------------------------------------------------
// kC: reduce 8 agg partials, vlad = agg - asum*cent, intra-normalize per
// (n,k) over C; global norm is exactly 8.  grid (16,64) = 1024 blocks,
// 256 thr, ONE k-row per wave.  float4 loads/stores.
// ---------------------------------------------------------------------------
__global__ __launch_bounds__(256) void kC(const float* __restrict__ aggP,
                                          const float* __restrict__ cent,
                                          const float* __restrict__ asumP,
                                          float* __restrict__ out) {
    __shared__ float asumS[4];
    const int t  = threadIdx.x;
    const int n  = blockIdx.y;
    const int k0 = blockIdx.x * 4;
    if (t < 4) {
        float s = 0.f;
        for (int j = 0; j < 8; ++j) s += asumP[((size_t)n * 8 + j) * 64 + k0 + t];
        asumS[t] = s;
    }
    __syncthreads();
    const int wv   = t >> 6;
    const int lane = t & 63;
    const int k    = k0 + wv;
    const float as = asumS[wv];
    const float* ab = aggP + ((size_t)n * 8 * 64 + k) * C_;   // partial p at +p*64*C_
    const float* cp = cent + (size_t)k * C_;
    float4v v[2];
    float ss = 0.f;
#pragma unroll
    for (int j = 0; j < 2; ++j) {
        const int c = 4 * lane + 256 * j;
        float4v val = {0.f, 0.f, 0.f, 0.f};
#pragma unroll
        for (int p = 0; p < 8; ++p)
            val = val + *(const float4v*)(ab + (size_t)p * 64 * C_ + c);
        float4v c4 = *(const float4v*)(cp + c);
#pragma unroll
        for (int e = 0; e < 4; ++e) {
            val[e] -= as * c4[e];
            ss += val[e] * val[e];
        }
        v[j] = val;
    }
#pragma unroll
    for (int off = 32; off; off >>= 1) ss += __shfl_xor(ss, off, 64);
    const float scale = 1.f / (fmaxf(sqrtf(ss), EPS_) * 8.f);
    float* op = out + (size_t)n * (K_ * C_) + (size_t)k * C_;
#pragma unroll
    for (int j = 0; j < 2; ++j) {
        float4v o = v[j];
#pragma unroll
        for (int e = 0; e < 4; ++e) o[e] *= scale;
        *(float4v*)(op + 4 * lane + 256 * j) = o;
    }
}

extern "C" void kernel_launch(void* const* d_in, const int* in_sizes, int n_in,
                              void* d_out, int out_size, void* d_ws, size_t ws_size,
                              hipStream_t stream) {
    (void)in_sizes; (void)n_in; (void)out_size; (void)ws_size;
    const float* x    = (const float*)d_in[0];   // (64, 512, 28, 28) fp32
    const float* w    = (const float*)d_in[1];   // (64, 512) fp32
    const float* cent = (const float*)d_in[2];   // (64, 512) fp32
    float* out = (float*)d_out;                  // (64, 32768) fp32

    // ws: aggP f32 [64 n][8 bx][64 k][512 c] = 67.1 MB ; asumP f32 [64][8][64]
    // = 128 KB.  Total 67.2 MB (ws allocation is ~411 MB per the fill resets).
    char* base = (char*)d_ws;
    float* aggP  = (float*)base;
    float* asumP = aggP + (size_t)64 * 8 * 64 * 512;

    kF<<<dim3(8, 64), 1024, 0, stream>>>(x, w, aggP, asumP);
    kC<<<dim3(16, 64), 256, 0, stream>>>(aggP, cent, asumP, out);
}

// Round 10
// 173.378 us; speedup vs baseline: 2.0346x; 2.0346x over previous
//
#include <hip/hip_runtime.h>

#define C_ 512
#define L_ 784
#define K_ 64
#define EPS_ 1e-12f

typedef _Float16 half_t;
typedef _Float16 half4 __attribute__((ext_vector_type(4)));
typedef float float4v __attribute__((ext_vector_type(4)));

// ---------------------------------------------------------------------------
// kF v8: ONE barrier per subtile (v5's lagged agg, made reg-safe by reading
// agg fragments back from the LDS x-stage instead of keeping them in regs).
// grid (4, 64), block 1024 (16 waves = 4 kt x 4 cs).  1 block/CU (structural:
// ~96 total regs/wave; r9 proved 2 blocks/CU => 64 regs => catastrophic spill).
//
// Buffers: xs fp16 4-deep (write s+2 in window s; read s+2 in window s+1 --
// barrier(s+1)-separated); sl double; ah double.  Skew-checked: every LDS
// write/read pair of a buffer is separated by >=1 barrier.
// Per 16-l subtile s (ONE barrier):
//   0. g0,g1 = dwordx4 loads of subtile s+2 (transient; sched_barrier pin)
//   1. logits(s): bn = ds_read xs[s&3]; T = mfma(bn,I); lc[i&3] += mfma(T,wf)
//   2. sl[s&1] partials; BARRIER
//   3. softmax(s): wave=l-row, lane=k, shfl_xor; ah[s&1][k][l]; asum
//   4. cvt g -> ds_write xs[(s+2)&3]
//   5. lagged agg(s-1): aA = ah[(s-1)&1]; bnp = ds_read xs[(s-1)&3];
//      agc[i] += mfma(aA, bnp)   (softmax(s-1) preceded barrier(s) in all waves)
// Tail: BARRIER; agg(NT-1).
// MFMA maps verified end-to-end r3/r4/r6/r7 (passed, absmax 1.2e-4):
//   A: m=lane&15, kk=q*4+j; B: n=lane&15, kk=q*4+j; D: row=q*4+r, col=lane&15.
// ---------------------------------------------------------------------------
__global__ __launch_bounds__(1024) void kF(const float* __restrict__ x,
                                           const float* __restrict__ w,
                                           float* __restrict__ aggP,
                                           float* __restrict__ asumP) {
    __shared__ half_t xs[4][32 * 256];    // 64 KB: [buf][tile = cs*8+i][slot*4] fp16
    __shared__ float  sl[2][16 * 64 * 4]; // 32 KB: [buf][l][k][cs] partials
    __shared__ half_t ah[2][64 * 20];     //  5 KB: [buf][k][16 l + pad]

    const int t    = threadIdx.x;
    const int n    = blockIdx.y;
    const int bx   = blockIdx.x;
    const int l0   = bx * 192;
    const int NT   = (bx == 3) ? 13 : 12;   // 3*192 + 208 = 784
    const int wv   = t >> 6;
    const int lane = t & 63;
    const int m16  = lane & 15;
    const int q    = lane >> 4;
    const int kt   = wv & 3;   // k-tile (16 k)
    const int cs   = wv >> 2;  // c-segment (128 c = 8 tiles of 16)

    const float* xn = x + (size_t)n * (C_ * L_);

    // staging: wave wv owns tiles T0 = 2wv, T0+1 (tile T: cs = T>>3, i = T&7)
    const int T0 = 2 * wv;
    const float* src0 = xn + (size_t)((T0 >> 3) * 128 + (T0 & 7) * 16 + m16) * L_ + l0 + 4 * q;
    const float* src1 = xn + (size_t)(((T0 + 1) >> 3) * 128 + ((T0 + 1) & 7) * 16 + m16) * L_ + l0 + 4 * q;

    // prologue: stage subtiles 0 and 1
#pragma unroll
    for (int s0 = 0; s0 < 2; ++s0) {
        float4v g0 = *(const float4v*)(src0 + 16 * s0);
        float4v g1 = *(const float4v*)(src1 + 16 * s0);
        *(half4*)&xs[s0][T0 * 256 + lane * 4] =
            half4{(half_t)g0[0], (half_t)g0[1], (half_t)g0[2], (half_t)g0[3]};
        *(half4*)&xs[s0][(T0 + 1) * 256 + lane * 4] =
            half4{(half_t)g1[0], (half_t)g1[1], (half_t)g1[2], (half_t)g1[3]};
    }

    // w fragments (B-style): lane m16 -> k row, elems j -> c = cs*128+i*16+4q+j
    half4 wf[8];
#pragma unroll
    for (int i = 0; i < 8; ++i) {
        float4v f = *(const float4v*)(w + (size_t)(kt * 16 + m16) * C_ +
                                      cs * 128 + i * 16 + 4 * q);
        wf[i] = half4{(half_t)f[0], (half_t)f[1], (half_t)f[2], (half_t)f[3]};
    }
    // identity B-fragment: I[kk=4q+j][n=m16]
    half4 ifr;
#pragma unroll
    for (int j = 0; j < 4; ++j) ifr[j] = (half_t)((4 * q + j == m16) ? 1.0f : 0.0f);

    const float4v z4 = {0.f, 0.f, 0.f, 0.f};
    float4v agc[8];
#pragma unroll
    for (int i = 0; i < 8; ++i) agc[i] = z4;
    float asum_reg = 0.f;

    __syncthreads();

    for (int s = 0; s < NT; ++s) {
        // 0. transient prefetch of subtile s+2 (written to LDS at step 4)
        float4v g0, g1;
        const bool pf = (s + 2 < NT);
        if (pf) {
            g0 = *(const float4v*)(src0 + 16 * (s + 2));
            g1 = *(const float4v*)(src1 + 16 * (s + 2));
        }
        __builtin_amdgcn_sched_barrier(0);   // pin load issue at loop top
        // 1. logits(s) from xs[s&3] (half4 fragments, transpose-MFMA trick)
        const half_t* xb = &xs[s & 3][(cs * 8) * 256];
        float4v lc[4] = {z4, z4, z4, z4};
#pragma unroll
        for (int i = 0; i < 8; ++i) {
            half4 bn = *(const half4*)&xb[i * 256 + lane * 4];
            float4v xt = __builtin_amdgcn_mfma_f32_16x16x16f16(bn, ifr, z4, 0, 0, 0);
            half4 a4 = {(half_t)xt[0], (half_t)xt[1], (half_t)xt[2], (half_t)xt[3]};
            lc[i & 3] = __builtin_amdgcn_mfma_f32_16x16x16f16(a4, wf[i], lc[i & 3], 0, 0, 0);
        }
        float4v lac = (lc[0] + lc[1]) + (lc[2] + lc[3]);
        // 2. D[l][k]: row 4q+r = l_local, col m16 = k_local
        float* slb = sl[s & 1];
#pragma unroll
        for (int r = 0; r < 4; ++r)
            slb[((4 * q + r) * 64 + kt * 16 + m16) * 4 + cs] = lac[r];
        __syncthreads();   // the ONLY barrier per subtile
        // 3. softmax(s): wave wv = l-row, lane = k
        {
            float4v p4 = *(const float4v*)&slb[(wv * 64 + lane) * 4];
            float lg = p4[0] + p4[1] + p4[2] + p4[3];
            float mx = lg;
#pragma unroll
            for (int off = 32; off; off >>= 1) mx = fmaxf(mx, __shfl_xor(mx, off, 64));
            float e = __expf(lg - mx);
            float sm = e;
#pragma unroll
            for (int off = 32; off; off >>= 1) sm += __shfl_xor(sm, off, 64);
            float a = e / sm;
            asum_reg += a;
            ah[s & 1][lane * 20 + wv] = (half_t)a;
        }
        // 4. write staged subtile s+2 (readers: logits(s+2), after barrier(s+1))
        if (pf) {
            *(half4*)&xs[(s + 2) & 3][T0 * 256 + lane * 4] =
                half4{(half_t)g0[0], (half_t)g0[1], (half_t)g0[2], (half_t)g0[3]};
            *(half4*)&xs[(s + 2) & 3][(T0 + 1) * 256 + lane * 4] =
                half4{(half_t)g1[0], (half_t)g1[1], (half_t)g1[2], (half_t)g1[3]};
        }
        // 5. lagged agg(s-1): ah[(s-1)&1] complete (softmax(s-1) preceded
        //    barrier(s)); x frags re-read from xs[(s-1)&3] (still resident).
        if (s > 0) {
            const half_t* xp = &xs[(s - 1) & 3][(cs * 8) * 256];
            half4 aA = *(const half4*)&ah[(s - 1) & 1][(kt * 16 + m16) * 20 + 4 * q];
#pragma unroll
            for (int i = 0; i < 8; ++i) {
                half4 bnp = *(const half4*)&xp[i * 256 + lane * 4];
                agc[i] = __builtin_amdgcn_mfma_f32_16x16x16f16(aA, bnp, agc[i], 0, 0, 0);
            }
        }
    }

    // tail: final subtile's agg (needs a barrier so ah[(NT-1)&1] is complete)
    __syncthreads();
    {
        const half_t* xp = &xs[(NT - 1) & 3][(cs * 8) * 256];
        half4 aA = *(const half4*)&ah[(NT - 1) & 1][(kt * 16 + m16) * 20 + 4 * q];
#pragma unroll
        for (int i = 0; i < 8; ++i) {
            half4 bnp = *(const half4*)&xp[i * 256 + lane * 4];
            agc[i] = __builtin_amdgcn_mfma_f32_16x16x16f16(aA, bnp, agc[i], 0, 0, 0);
        }
    }

    // ---- epilogue: asum reduce (sl[0] reused) + direct coalesced agg stores ----
    float* red = sl[0];
    __syncthreads();
    red[wv * 64 + lane] = asum_reg;
    __syncthreads();
    if (t < 64) {
        float s_ = 0.f;
#pragma unroll
        for (int j = 0; j < 16; ++j) s_ += red[j * 64 + t];
        asumP[((size_t)n * 4 + bx) * 64 + t] = s_;
    }
    float* ap = aggP + (((size_t)n * 4 + bx) * 64) * (size_t)C_;
#pragma unroll
    for (int i = 0; i < 8; ++i)
#pragma unroll
        for (int r = 0; r < 4; ++r)
            ap[(size_t)(kt * 16 + 4 * q + r) * C_ + (cs * 8 + i) * 16 + m16] = agc[i][r];
}

// ---------------------------------------------------------------------------
// kC: reduce 4 agg partials, vlad = agg - asum*cent, intra-normalize per
// (n,k) over C; global norm is exactly 8.  grid (16,64) = 1024 blocks,
// 256 thr, ONE k-row per wave.  float4 loads/stores.
// ---------------------------------------------------------------------------
__global__ __launch_bounds__(256) void kC(const float* __restrict__ aggP,
                                          const float* __restrict__ cent,
                                          const float* __restrict__ asumP,
                                          float* __restrict__ out) {
    __shared__ float asumS[4];
    const int t  = threadIdx.x;
    const int n  = blockIdx.y;
    const int k0 = blockIdx.x * 4;
    if (t < 4) {
        float s = 0.f;
        for (int j = 0; j < 4; ++j) s += asumP[((size_t)n * 4 + j) * 64 + k0 + t];
        asumS[t] = s;
    }
    __syncthreads();
    const int wv   = t >> 6;
    const int lane = t & 63;
    const int k    = k0 + wv;
    const float as = asumS[wv];
    const float* a0 = aggP + (((size_t)n * 4 + 0) * 64 + k) * C_;
    const float* a1 = aggP + (((size_t)n * 4 + 1) * 64 + k) * C_;
    const float* a2 = aggP + (((size_t)n * 4 + 2) * 64 + k) * C_;
    const float* a3 = aggP + (((size_t)n * 4 + 3) * 64 + k) * C_;
    const float* cp = cent + (size_t)k * C_;
    float4v v[2];
    float ss = 0.f;
#pragma unroll
    for (int j = 0; j < 2; ++j) {
        const int c = 4 * lane + 256 * j;
        float4v val = *(const float4v*)(a0 + c);
        val = val + *(const float4v*)(a1 + c);
        val = val + *(const float4v*)(a2 + c);
        val = val + *(const float4v*)(a3 + c);
        float4v c4 = *(const float4v*)(cp + c);
#pragma unroll
        for (int e = 0; e < 4; ++e) {
            val[e] -= as * c4[e];
            ss += val[e] * val[e];
        }
        v[j] = val;
    }
#pragma unroll
    for (int off = 32; off; off >>= 1) ss += __shfl_xor(ss, off, 64);
    const float scale = 1.f / (fmaxf(sqrtf(ss), EPS_) * 8.f);
    float* op = out + (size_t)n * (K_ * C_) + (size_t)k * C_;
#pragma unroll
    for (int j = 0; j < 2; ++j) {
        float4v o = v[j];
#pragma unroll
        for (int e = 0; e < 4; ++e) o[e] *= scale;
        *(float4v*)(op + 4 * lane + 256 * j) = o;
    }
}

extern "C" void kernel_launch(void* const* d_in, const int* in_sizes, int n_in,
                              void* d_out, int out_size, void* d_ws, size_t ws_size,
                              hipStream_t stream) {
    (void)in_sizes; (void)n_in; (void)out_size; (void)ws_size;
    const float* x    = (const float*)d_in[0];   // (64, 512, 28, 28) fp32
    const float* w    = (const float*)d_in[1];   // (64, 512) fp32
    const float* cent = (const float*)d_in[2];   // (64, 512) fp32
    float* out = (float*)d_out;                  // (64, 32768) fp32

    // ws: aggP f32 [64 n][4 bx][64 k][512 c] = 33.6 MB ; asumP f32 [64][4][64]
    // = 64 KB.  Total 33.7 MB.
    char* base = (char*)d_ws;
    float* aggP  = (float*)base;
    float* asumP = aggP + (size_t)64 * 4 * 64 * 512;

    kF<<<dim3(4, 64), 1024, 0, stream>>>(x, w, aggP, asumP);
    kC<<<dim3(16, 64), 256, 0, stream>>>(aggP, cent, asumP, out);
}

// Round 11
// 171.323 us; speedup vs baseline: 2.0590x; 1.0120x over previous
//
#include <hip/hip_runtime.h>

#define C_ 512
#define L_ 784
#define K_ 64
#define EPS_ 1e-12f
#define SLS 264   // sl row stride in floats: 264 % 32 == 8 -> q-groups hit
                  // distinct bank sets (was 256 == 0 mod 32: 8-way conflict)

typedef _Float16 half_t;
typedef _Float16 half4 __attribute__((ext_vector_type(4)));
typedef float float4v __attribute__((ext_vector_type(4)));

// ---------------------------------------------------------------------------
// kF v9 = v8 (1 barrier/subtile, lagged agg, LDS-reread fragments) + 3 safe
// micro-fixes from the r10 counters:
//   (1) sl padded to stride 264 -> kills the 8-way bank conflict on the
//       partial-logits stores (SQ_LDS_BANK_CONFLICT 1.4M cyc, ~2.3 us/CU)
//   (2) logits scaled by log2e PRE-barrier; softmax uses exp2f -> one fewer
//       dependent VALU in the post-barrier serial chain
//   (3) one redundant epilogue barrier removed
// grid (4, 64), block 1024 (16 waves = 4 kt x 4 cs).  1 block/CU structural
// (co-residency proven infeasible: r9 = 64-reg spill disaster at 2 blk/CU).
// Per 16-l subtile s (ONE barrier):
//   0. g0,g1 = dwordx4 loads of subtile s+2 (transient; sched_barrier pin)
//   1. logits(s): bn = ds_read xs[s&3]; T = mfma(bn,I); lc[i&3] += mfma(T,wf)
//   2. sl[s&1] partials (xlog2e); BARRIER
//   3. softmax(s): wave=l-row, lane=k, shfl_xor trees, exp2; ah[s&1]; asum
//   4. cvt g -> ds_write xs[(s+2)&3]
//   5. lagged agg(s-1): agc[i] += mfma(ah[(s-1)&1], ds_read xs[(s-1)&3])
// Buffer skew (all write/read pairs >=1 barrier apart): xs 4-deep, sl/ah 2-deep.
// MFMA maps verified end-to-end r3-r10 (passed, absmax 1.2e-4):
//   A: m=lane&15, kk=q*4+j; B: n=lane&15, kk=q*4+j; D: row=q*4+r, col=lane&15.
// ---------------------------------------------------------------------------
__global__ __launch_bounds__(1024) void kF(const float* __restrict__ x,
                                           const float* __restrict__ w,
                                           float* __restrict__ aggP,
                                           float* __restrict__ asumP) {
    __shared__ half_t xs[4][32 * 256];    // 64 KB: [buf][tile = cs*8+i][slot*4] fp16
    __shared__ float  sl[2][16 * SLS];    // 33 KB: [buf][l][k*4+cs] padded partials
    __shared__ half_t ah[2][64 * 20];     //  5 KB: [buf][k][16 l + pad]

    const int t    = threadIdx.x;
    const int n    = blockIdx.y;
    const int bx   = blockIdx.x;
    const int l0   = bx * 192;
    const int NT   = (bx == 3) ? 13 : 12;   // 3*192 + 208 = 784
    const int wv   = t >> 6;
    const int lane = t & 63;
    const int m16  = lane & 15;
    const int q    = lane >> 4;
    const int kt   = wv & 3;   // k-tile (16 k)
    const int cs   = wv >> 2;  // c-segment (128 c = 8 tiles of 16)

    const float* xn = x + (size_t)n * (C_ * L_);

    // staging: wave wv owns tiles T0 = 2wv, T0+1 (tile T: cs = T>>3, i = T&7)
    const int T0 = 2 * wv;
    const float* src0 = xn + (size_t)((T0 >> 3) * 128 + (T0 & 7) * 16 + m16) * L_ + l0 + 4 * q;
    const float* src1 = xn + (size_t)(((T0 + 1) >> 3) * 128 + ((T0 + 1) & 7) * 16 + m16) * L_ + l0 + 4 * q;

    // prologue: stage subtiles 0 and 1
#pragma unroll
    for (int s0 = 0; s0 < 2; ++s0) {
        float4v g0 = *(const float4v*)(src0 + 16 * s0);
        float4v g1 = *(const float4v*)(src1 + 16 * s0);
        *(half4*)&xs[s0][T0 * 256 + lane * 4] =
            half4{(half_t)g0[0], (half_t)g0[1], (half_t)g0[2], (half_t)g0[3]};
        *(half4*)&xs[s0][(T0 + 1) * 256 + lane * 4] =
            half4{(half_t)g1[0], (half_t)g1[1], (half_t)g1[2], (half_t)g1[3]};
    }

    // w fragments (B-style): lane m16 -> k row, elems j -> c = cs*128+i*16+4q+j
    half4 wf[8];
#pragma unroll
    for (int i = 0; i < 8; ++i) {
        float4v f = *(const float4v*)(w + (size_t)(kt * 16 + m16) * C_ +
                                      cs * 128 + i * 16 + 4 * q);
        wf[i] = half4{(half_t)f[0], (half_t)f[1], (half_t)f[2], (half_t)f[3]};
    }
    // identity B-fragment: I[kk=4q+j][n=m16]
    half4 ifr;
#pragma unroll
    for (int j = 0; j < 4; ++j) ifr[j] = (half_t)((4 * q + j == m16) ? 1.0f : 0.0f);

    const float4v z4 = {0.f, 0.f, 0.f, 0.f};
    const float LOG2E = 1.4426950408889634f;
    float4v agc[8];
#pragma unroll
    for (int i = 0; i < 8; ++i) agc[i] = z4;
    float asum_reg = 0.f;

    __syncthreads();

    for (int s = 0; s < NT; ++s) {
        // 0. transient prefetch of subtile s+2 (written to LDS at step 4)
        float4v g0, g1;
        const bool pf = (s + 2 < NT);
        if (pf) {
            g0 = *(const float4v*)(src0 + 16 * (s + 2));
            g1 = *(const float4v*)(src1 + 16 * (s + 2));
        }
        __builtin_amdgcn_sched_barrier(0);   // pin load issue at loop top
        // 1. logits(s) from xs[s&3] (half4 fragments, transpose-MFMA trick)
        const half_t* xb = &xs[s & 3][(cs * 8) * 256];
        float4v lc[4] = {z4, z4, z4, z4};
#pragma unroll
        for (int i = 0; i < 8; ++i) {
            half4 bn = *(const half4*)&xb[i * 256 + lane * 4];
            float4v xt = __builtin_amdgcn_mfma_f32_16x16x16f16(bn, ifr, z4, 0, 0, 0);
            half4 a4 = {(half_t)xt[0], (half_t)xt[1], (half_t)xt[2], (half_t)xt[3]};
            lc[i & 3] = __builtin_amdgcn_mfma_f32_16x16x16f16(a4, wf[i], lc[i & 3], 0, 0, 0);
        }
        float4v lac = (lc[0] + lc[1]) + (lc[2] + lc[3]);
        // 2. D[l][k] partials in log2 domain: row 4q+r = l_local, col m16 = k
        float* slb = sl[s & 1];
#pragma unroll
        for (int r = 0; r < 4; ++r)
            slb[(4 * q + r) * SLS + (kt * 16 + m16) * 4 + cs] = lac[r] * LOG2E;
        __syncthreads();   // the ONLY barrier per subtile
        // 3. softmax(s): wave wv = l-row, lane = k (log2-domain: exp2)
        {
            float4v p4 = *(const float4v*)&slb[wv * SLS + lane * 4];
            float lg = p4[0] + p4[1] + p4[2] + p4[3];
            float mx = lg;
#pragma unroll
            for (int off = 32; off; off >>= 1) mx = fmaxf(mx, __shfl_xor(mx, off, 64));
            float e = exp2f(lg - mx);
            float sm = e;
#pragma unroll
            for (int off = 32; off; off >>= 1) sm += __shfl_xor(sm, off, 64);
            float a = e / sm;
            asum_reg += a;
            ah[s & 1][lane * 20 + wv] = (half_t)a;
        }
        // 4. write staged subtile s+2 (readers: logits(s+2), after barrier(s+1))
        if (pf) {
            *(half4*)&xs[(s + 2) & 3][T0 * 256 + lane * 4] =
                half4{(half_t)g0[0], (half_t)g0[1], (half_t)g0[2], (half_t)g0[3]};
            *(half4*)&xs[(s + 2) & 3][(T0 + 1) * 256 + lane * 4] =
                half4{(half_t)g1[0], (half_t)g1[1], (half_t)g1[2], (half_t)g1[3]};
        }
        // 5. lagged agg(s-1): ah[(s-1)&1] complete (softmax(s-1) preceded
        //    barrier(s)); x frags re-read from xs[(s-1)&3] (still resident).
        if (s > 0) {
            const half_t* xp = &xs[(s - 1) & 3][(cs * 8) * 256];
            half4 aA = *(const half4*)&ah[(s - 1) & 1][(kt * 16 + m16) * 20 + 4 * q];
#pragma unroll
            for (int i = 0; i < 8; ++i) {
                half4 bnp = *(const half4*)&xp[i * 256 + lane * 4];
                agc[i] = __builtin_amdgcn_mfma_f32_16x16x16f16(aA, bnp, agc[i], 0, 0, 0);
            }
        }
    }

    // tail: final subtile's agg (barrier so ah[(NT-1)&1] is visible)
    __syncthreads();
    {
        const half_t* xp = &xs[(NT - 1) & 3][(cs * 8) * 256];
        half4 aA = *(const half4*)&ah[(NT - 1) & 1][(kt * 16 + m16) * 20 + 4 * q];
#pragma unroll
        for (int i = 0; i < 8; ++i) {
            half4 bnp = *(const half4*)&xp[i * 256 + lane * 4];
            agc[i] = __builtin_amdgcn_mfma_f32_16x16x16f16(aA, bnp, agc[i], 0, 0, 0);
        }
    }

    // ---- epilogue: asum reduce + direct coalesced agg stores ----
    // sl[0]'s last reader was softmax(NT-1) or earlier, all pre-tail-barrier:
    // safe to overwrite without an extra barrier.
    float* red = sl[0];
    red[wv * 64 + lane] = asum_reg;
    __syncthreads();
    if (t < 64) {
        float s_ = 0.f;
#pragma unroll
        for (int j = 0; j < 16; ++j) s_ += red[j * 64 + t];
        asumP[((size_t)n * 4 + bx) * 64 + t] = s_;
    }
    float* ap = aggP + (((size_t)n * 4 + bx) * 64) * (size_t)C_;
#pragma unroll
    for (int i = 0; i < 8; ++i)
#pragma unroll
        for (int r = 0; r < 4; ++r)
            ap[(size_t)(kt * 16 + 4 * q + r) * C_ + (cs * 8 + i) * 16 + m16] = agc[i][r];
}

// ---------------------------------------------------------------------------
// kC: reduce 4 agg partials, vlad = agg - asum*cent, intra-normalize per
// (n,k) over C; global norm is exactly 8.  grid (16,64) = 1024 blocks,
// 256 thr, ONE k-row per wave.  float4 loads/stores.
// ---------------------------------------------------------------------------
__global__ __launch_bounds__(256) void kC(const float* __restrict__ aggP,
                                          const float* __restrict__ cent,
                                          const float* __restrict__ asumP,
                                          float* __restrict__ out) {
    __shared__ float asumS[4];
    const int t  = threadIdx.x;
    const int n  = blockIdx.y;
    const int k0 = blockIdx.x * 4;
    if (t < 4) {
        float s = 0.f;
        for (int j = 0; j < 4; ++j) s += asumP[((size_t)n * 4 + j) * 64 + k0 + t];
        asumS[t] = s;
    }
    __syncthreads();
    const int wv   = t >> 6;
    const int lane = t & 63;
    const int k    = k0 + wv;
    const float as = asumS[wv];
    const float* a0 = aggP + (((size_t)n * 4 + 0) * 64 + k) * C_;
    const float* a1 = aggP + (((size_t)n * 4 + 1) * 64 + k) * C_;
    const float* a2 = aggP + (((size_t)n * 4 + 2) * 64 + k) * C_;
    const float* a3 = aggP + (((size_t)n * 4 + 3) * 64 + k) * C_;
    const float* cp = cent + (size_t)k * C_;
    float4v v[2];
    float ss = 0.f;
#pragma unroll
    for (int j = 0; j < 2; ++j) {
        const int c = 4 * lane + 256 * j;
        float4v val = *(const float4v*)(a0 + c);
        val = val + *(const float4v*)(a1 + c);
        val = val + *(const float4v*)(a2 + c);
        val = val + *(const float4v*)(a3 + c);
        float4v c4 = *(const float4v*)(cp + c);
#pragma unroll
        for (int e = 0; e < 4; ++e) {
            val[e] -= as * c4[e];
            ss += val[e] * val[e];
        }
        v[j] = val;
    }
#pragma unroll
    for (int off = 32; off; off >>= 1) ss += __shfl_xor(ss, off, 64);
    const float scale = 1.f / (fmaxf(sqrtf(ss), EPS_) * 8.f);
    float* op = out + (size_t)n * (K_ * C_) + (size_t)k * C_;
#pragma unroll
    for (int j = 0; j < 2; ++j) {
        float4v o = v[j];
#pragma unroll
        for (int e = 0; e < 4; ++e) o[e] *= scale;
        *(float4v*)(op + 4 * lane + 256 * j) = o;
    }
}

extern "C" void kernel_launch(void* const* d_in, const int* in_sizes, int n_in,
                              void* d_out, int out_size, void* d_ws, size_t ws_size,
                              hipStream_t stream) {
    (void)in_sizes; (void)n_in; (void)out_size; (void)ws_size;
    const float* x    = (const float*)d_in[0];   // (64, 512, 28, 28) fp32
    const float* w    = (const float*)d_in[1];   // (64, 512) fp32
    const float* cent = (const float*)d_in[2];   // (64, 512) fp32
    float* out = (float*)d_out;                  // (64, 32768) fp32

    // ws: aggP f32 [64 n][4 bx][64 k][512 c] = 33.6 MB ; asumP f32 [64][4][64]
    // = 64 KB.  Total 33.7 MB.
    char* base = (char*)d_ws;
    float* aggP  = (float*)base;
    float* asumP = aggP + (size_t)64 * 4 * 64 * 512;

    kF<<<dim3(4, 64), 1024, 0, stream>>>(x, w, aggP, asumP);
    kC<<<dim3(16, 64), 256, 0, stream>>>(aggP, cent, asumP, out);
}